// Round 2
// baseline (912.406 us; speedup 1.0000x reference)
//
#include <hip/hip_runtime.h>
#include <math.h>

#define BB 512   // batch
#define TT 1024  // max seq len
#define HH 128   // hidden

// ---------------------------------------------------------------------------
// Kernel 1: bitonic sort of (length, idx) composite keys, descending.
// Load-balance only; any permutation is still correct.
// ---------------------------------------------------------------------------
__global__ __launch_bounds__(512) void sort_kernel(const int* __restrict__ lengths,
                                                   int* __restrict__ order) {
  __shared__ int comp[BB];
  const int t = threadIdx.x;
  comp[t] = (lengths[t] << 9) | t;  // unique composite keys
  __syncthreads();
  for (int k = 2; k <= BB; k <<= 1) {
    for (int j = k >> 1; j > 0; j >>= 1) {
      int ixj = t ^ j;
      if (ixj > t) {
        int a = comp[t], b = comp[ixj];
        bool descBlock = ((t & k) == 0);
        bool doSwap = descBlock ? (a < b) : (a > b);
        if (doSwap) { comp[t] = b; comp[ixj] = a; }
      }
      __syncthreads();
    }
  }
  order[t] = comp[t] & 511;
}

// ---------------------------------------------------------------------------
// Kernel 2: GRU recurrence. 256 blocks x 512 threads (8 waves).
// Wave w: kc = w>>1 (wave-uniform K-chunk of 32), rows (w&1)*64 + lane.
// Phase 1: h chunk broadcast via v_readlane -> SGPR, 96 reg-resident-weight
//          FMAs per thread, partials to LDS.
// Phase 2: threads 0..127 reduce 4 partials/gate + gates + h update.
// Weights pinned in VGPRs with an opaque asm barrier (round-1 showed the
// compiler sank them into the loop: VGPR_Count was 80 < the 96 needed).
// ---------------------------------------------------------------------------
__global__ __launch_bounds__(512, 2) void gru_main(
    const float* __restrict__ x, const int* __restrict__ lengths,
    const float* __restrict__ w_ih, const float* __restrict__ w_hh,
    const float* __restrict__ b_ih, const float* __restrict__ b_hh,
    const float* __restrict__ head_w, const float* __restrict__ head_b,
    const int* __restrict__ order, float* __restrict__ out) {
  __shared__ __align__(16) float hs[HH];        // current hidden state
  __shared__ float parts[3][4][HH];             // split-K partials
  __shared__ __align__(16) float xrow[TT * 2];  // staged x row (8 KB)

  const int tid  = threadIdx.x;
  const int lane = tid & 63;
  const int wave = tid >> 6;
  const int kc   = wave >> 1;         // wave-uniform K-chunk (0..3)
  const int rg   = wave & 1;          // row-group (0..1)
  const int irow = rg * 64 + lane;    // output row within a gate, 0..127
  const int kbase = kc * 32;

  // --- one-time: w_hh chunk into registers, pinned ---
  float wr[32], wz[32], wn[32];
#pragma unroll
  for (int j = 0; j < 32; ++j) {
    wr[j] = w_hh[(0 * HH + irow) * HH + kbase + j];
    wz[j] = w_hh[(1 * HH + irow) * HH + kbase + j];
    wn[j] = w_hh[(2 * HH + irow) * HH + kbase + j];
  }
#pragma unroll
  for (int j = 0; j < 32; ++j) {
    asm volatile("" : "+v"(wr[j]), "+v"(wz[j]), "+v"(wn[j]));
  }

  // --- phase-2 constants (used by threads 0..127; loaded harmlessly by all) ---
  const int i2 = tid & (HH - 1);
  float wi0[3], wi1[3], bi[3], bh[3];
#pragma unroll
  for (int g = 0; g < 3; ++g) {
    wi0[g] = w_ih[(g * HH + i2) * 2 + 0];
    wi1[g] = w_ih[(g * HH + i2) * 2 + 1];
    bi[g]  = b_ih[g * HH + i2];
    bh[g]  = b_hh[g * HH + i2];
  }
  const float hw = head_w[i2];
  const float hb = head_b[0];

  // fixed LDS addresses for phase 1
  const int haddr = kbase + (lane & 31);  // lanes 0-31 / 32-63 duplicate: free

  for (int pb = 0; pb < 2; ++pb) {
    const int slot = pb ? (BB - 1 - (int)blockIdx.x) : (int)blockIdx.x;
    const int b = order[slot];
    const int len = lengths[b];  // in [1, 1024]

    // stage this batch's x row (coalesced) + init h
    for (int ofs = tid; ofs < len * 2; ofs += 512)
      xrow[ofs] = x[(size_t)b * (TT * 2) + ofs];
    if (tid < HH) hs[tid] = 0.0f;
    __syncthreads();

    for (int t = 0; t < len; ++t) {
      // ---- phase 1: wave-uniform-chunk matvec, SGPR broadcast ----
      const float hreg = hs[haddr];
      float pr = 0.f, pz = 0.f, pn = 0.f;
#pragma unroll
      for (int j = 0; j < 32; ++j) {
        const float s = __int_as_float(
            __builtin_amdgcn_readlane(__float_as_int(hreg), j));
        pr = fmaf(s, wr[j], pr);
        pz = fmaf(s, wz[j], pz);
        pn = fmaf(s, wn[j], pn);
      }
      parts[0][kc][irow] = pr;
      parts[1][kc][irow] = pz;
      parts[2][kc][irow] = pn;
      __syncthreads();

      // ---- phase 2: reduce + gates + h update, threads 0..127 ----
      if (tid < HH) {
        float gr = bh[0] + parts[0][0][tid] + parts[0][1][tid] +
                   parts[0][2][tid] + parts[0][3][tid];
        float gz = bh[1] + parts[1][0][tid] + parts[1][1][tid] +
                   parts[1][2][tid] + parts[1][3][tid];
        float gn = bh[2] + parts[2][0][tid] + parts[2][1][tid] +
                   parts[2][2][tid] + parts[2][3][tid];
        const float x0 = xrow[t * 2 + 0];
        const float x1 = xrow[t * 2 + 1];
        const float ar = bi[0] + x0 * wi0[0] + x1 * wi1[0] + gr;
        const float az = bi[1] + x0 * wi0[1] + x1 * wi1[1] + gz;
        const float an = bi[2] + x0 * wi0[2] + x1 * wi1[2];
        const float r = 1.0f / (1.0f + __expf(-ar));
        const float z = 1.0f / (1.0f + __expf(-az));
        const float a = an + r * gn;          // tanh argument
        const float e2 = __expf(-2.0f * a);
        const float n = (1.0f - e2) / (1.0f + e2);
        hs[tid] = (1.0f - z) * n + z * hs[tid];
      }
      __syncthreads();
    }

    // ---- head: out[b] = dot(h, head_w) + head_b ----
    if (tid < HH) parts[0][0][tid] = hs[tid] * hw;
    __syncthreads();
    if (tid == 0) {
      float s = hb;
      for (int q = 0; q < HH; ++q) s += parts[0][0][q];
      out[b] = s;
    }
    __syncthreads();  // protect hs/parts before next batch reuses them
  }
}

extern "C" void kernel_launch(void* const* d_in, const int* in_sizes, int n_in,
                              void* d_out, int out_size, void* d_ws, size_t ws_size,
                              hipStream_t stream) {
  const float* x       = (const float*)d_in[0];
  const int*   lengths = (const int*)d_in[1];
  const float* w_ih    = (const float*)d_in[2];
  const float* w_hh    = (const float*)d_in[3];
  const float* b_ih    = (const float*)d_in[4];
  const float* b_hh    = (const float*)d_in[5];
  const float* head_w  = (const float*)d_in[6];
  const float* head_b  = (const float*)d_in[7];
  float* out = (float*)d_out;
  int* order = (int*)d_ws;  // 512 ints of scratch

  sort_kernel<<<1, 512, 0, stream>>>(lengths, order);
  gru_main<<<256, 512, 0, stream>>>(x, lengths, w_ih, w_hh, b_ih, b_hh,
                                    head_w, head_b, order, out);
}

// Round 3
// 705.726 us; speedup vs baseline: 1.2929x; 1.2929x over previous
//
#include <hip/hip_runtime.h>
#include <math.h>

#define BB 512   // batch
#define TT 1024  // max seq len
#define HH 128   // hidden

// ---------------------------------------------------------------------------
// Kernel 1: bitonic sort of (length, idx) composite keys, descending.
// Load-balance only; any permutation is still correct.
// ---------------------------------------------------------------------------
__global__ __launch_bounds__(512) void sort_kernel(const int* __restrict__ lengths,
                                                   int* __restrict__ order) {
  __shared__ int comp[BB];
  const int t = threadIdx.x;
  comp[t] = (lengths[t] << 9) | t;  // unique composite keys
  __syncthreads();
  for (int k = 2; k <= BB; k <<= 1) {
    for (int j = k >> 1; j > 0; j >>= 1) {
      int ixj = t ^ j;
      if (ixj > t) {
        int a = comp[t], b = comp[ixj];
        bool descBlock = ((t & k) == 0);
        bool doSwap = descBlock ? (a < b) : (a > b);
        if (doSwap) { comp[t] = b; comp[ixj] = a; }
      }
      __syncthreads();
    }
  }
  order[t] = comp[t] & 511;
}

// ---------------------------------------------------------------------------
// Kernel 2: GRU recurrence. 256 blocks x 512 threads (8 waves), one block/CU.
// Thread (i = tid&127, kc = tid>>7): split-K matvec, weights register-
// resident (96 VGPRs/thread = exactly the whole 192KB w_hh across the CU).
// Weights are pinned by empty asm register constraints INSIDE the t-loop:
// rounds 1-2 proved an out-of-loop pin lets the allocator rematerialize the
// global loads per step (VGPR_Count was 76-80 < the 96 needed -> ~1.5K
// cyc/step of L2 re-fetch, the measured bottleneck).
// ---------------------------------------------------------------------------
__global__ __launch_bounds__(512, 2) void gru_main(
    const float* __restrict__ x, const int* __restrict__ lengths,
    const float* __restrict__ w_ih, const float* __restrict__ w_hh,
    const float* __restrict__ b_ih, const float* __restrict__ b_hh,
    const float* __restrict__ head_w, const float* __restrict__ head_b,
    const int* __restrict__ order, float* __restrict__ out) {
  __shared__ __align__(16) float hs[HH];        // current hidden state
  __shared__ float parts[3][4][HH];             // split-K partials
  __shared__ __align__(16) float xrow[TT * 2];  // staged x row (8 KB)

  const int tid = threadIdx.x;
  const int i  = tid & (HH - 1);  // output row within a gate
  const int kc = tid >> 7;        // k-chunk 0..3 (wave-pair uniform)

  // --- one-time: weights into registers ---
  float4 wv[3][8];  // wv[g][q] = w_hh[g*128 + i][kc*32 + 4q .. +3]
#pragma unroll
  for (int g = 0; g < 3; ++g)
#pragma unroll
    for (int q = 0; q < 8; ++q)
      wv[g][q] = *reinterpret_cast<const float4*>(
          &w_hh[(g * HH + i) * HH + kc * 32 + q * 4]);

  // --- phase-2 constants ---
  float wi0[3], wi1[3], bi[3], bh[3];
#pragma unroll
  for (int g = 0; g < 3; ++g) {
    wi0[g] = w_ih[(g * HH + i) * 2 + 0];
    wi1[g] = w_ih[(g * HH + i) * 2 + 1];
    bi[g]  = b_ih[g * HH + i];
    bh[g]  = b_hh[g * HH + i];
  }
  const float hw = head_w[i];
  const float hb = head_b[0];

  for (int pb = 0; pb < 2; ++pb) {
    const int slot = pb ? (BB - 1 - (int)blockIdx.x) : (int)blockIdx.x;
    const int b = order[slot];
    const int len = lengths[b];  // in [1, 1024]

    // stage this batch's x row (coalesced) + init h
    for (int ofs = tid; ofs < len * 2; ofs += 512)
      xrow[ofs] = x[(size_t)b * (TT * 2) + ofs];
    if (tid < HH) hs[tid] = 0.0f;
    __syncthreads();

    for (int t = 0; t < len; ++t) {
      // ---- pin the 96 weight VGPRs live-through-loop (emits nothing) ----
#pragma unroll
      for (int g = 0; g < 3; ++g)
#pragma unroll
        for (int q = 0; q < 8; ++q)
          asm volatile("" : "+v"(wv[g][q].x), "+v"(wv[g][q].y),
                            "+v"(wv[g][q].z), "+v"(wv[g][q].w));

      // ---- phase 1: split-K matvec (h chunk broadcast within wave) ----
      float4 h4[8];
#pragma unroll
      for (int q = 0; q < 8; ++q)
        h4[q] = *reinterpret_cast<const float4*>(&hs[kc * 32 + q * 4]);
      float pr = 0.f, pz = 0.f, pn = 0.f;
#pragma unroll
      for (int q = 0; q < 8; ++q) {
        pr = fmaf(wv[0][q].x, h4[q].x, pr); pr = fmaf(wv[0][q].y, h4[q].y, pr);
        pr = fmaf(wv[0][q].z, h4[q].z, pr); pr = fmaf(wv[0][q].w, h4[q].w, pr);
        pz = fmaf(wv[1][q].x, h4[q].x, pz); pz = fmaf(wv[1][q].y, h4[q].y, pz);
        pz = fmaf(wv[1][q].z, h4[q].z, pz); pz = fmaf(wv[1][q].w, h4[q].w, pz);
        pn = fmaf(wv[2][q].x, h4[q].x, pn); pn = fmaf(wv[2][q].y, h4[q].y, pn);
        pn = fmaf(wv[2][q].z, h4[q].z, pn); pn = fmaf(wv[2][q].w, h4[q].w, pn);
      }
      parts[0][kc][i] = pr;
      parts[1][kc][i] = pz;
      parts[2][kc][i] = pn;
      __syncthreads();

      // ---- phase 2: reduce + gates + h update, threads 0..127 ----
      if (tid < HH) {
        float gr = bh[0] + parts[0][0][tid] + parts[0][1][tid] +
                   parts[0][2][tid] + parts[0][3][tid];
        float gz = bh[1] + parts[1][0][tid] + parts[1][1][tid] +
                   parts[1][2][tid] + parts[1][3][tid];
        float gn = bh[2] + parts[2][0][tid] + parts[2][1][tid] +
                   parts[2][2][tid] + parts[2][3][tid];
        const float x0 = xrow[t * 2 + 0];
        const float x1 = xrow[t * 2 + 1];
        const float ar = bi[0] + x0 * wi0[0] + x1 * wi1[0] + gr;
        const float az = bi[1] + x0 * wi0[1] + x1 * wi1[1] + gz;
        const float an = bi[2] + x0 * wi0[2] + x1 * wi1[2];
        const float r = 1.0f / (1.0f + __expf(-ar));
        const float z = 1.0f / (1.0f + __expf(-az));
        const float a = an + r * gn;          // tanh argument
        const float e2 = __expf(-2.0f * a);
        const float n = (1.0f - e2) / (1.0f + e2);
        hs[tid] = (1.0f - z) * n + z * hs[tid];
      }
      __syncthreads();
    }

    // ---- head: out[b] = dot(h, head_w) + head_b ----
    if (tid < HH) parts[0][0][tid] = hs[tid] * hw;
    __syncthreads();
    if (tid == 0) {
      float s = hb;
      for (int q = 0; q < HH; ++q) s += parts[0][0][q];
      out[b] = s;
    }
    __syncthreads();  // protect hs/parts before next batch reuses them
  }
}

extern "C" void kernel_launch(void* const* d_in, const int* in_sizes, int n_in,
                              void* d_out, int out_size, void* d_ws, size_t ws_size,
                              hipStream_t stream) {
  const float* x       = (const float*)d_in[0];
  const int*   lengths = (const int*)d_in[1];
  const float* w_ih    = (const float*)d_in[2];
  const float* w_hh    = (const float*)d_in[3];
  const float* b_ih    = (const float*)d_in[4];
  const float* b_hh    = (const float*)d_in[5];
  const float* head_w  = (const float*)d_in[6];
  const float* head_b  = (const float*)d_in[7];
  float* out = (float*)d_out;
  int* order = (int*)d_ws;  // 512 ints of scratch

  sort_kernel<<<1, 512, 0, stream>>>(lengths, order);
  gru_main<<<256, 512, 0, stream>>>(x, lengths, w_ih, w_hh, b_ih, b_hh,
                                    head_w, head_b, order, out);
}

// Round 5
// 681.613 us; speedup vs baseline: 1.3386x; 1.0354x over previous
//
#include <hip/hip_runtime.h>
#include <math.h>

#define BB 512   // batch
#define TT 1024  // max seq len
#define HH 128   // hidden

// ---------------------------------------------------------------------------
// Kernel 1: bitonic sort of (length, idx) composite keys, descending.
// Load-balance only; any permutation is still correct.
// ---------------------------------------------------------------------------
__global__ __launch_bounds__(512) void sort_kernel(const int* __restrict__ lengths,
                                                   int* __restrict__ order) {
  __shared__ int comp[BB];
  const int t = threadIdx.x;
  comp[t] = (lengths[t] << 9) | t;  // unique composite keys
  __syncthreads();
  for (int k = 2; k <= BB; k <<= 1) {
    for (int j = k >> 1; j > 0; j >>= 1) {
      int ixj = t ^ j;
      if (ixj > t) {
        int a = comp[t], b = comp[ixj];
        bool descBlock = ((t & k) == 0);
        bool doSwap = descBlock ? (a < b) : (a > b);
        if (doSwap) { comp[t] = b; comp[ixj] = a; }
      }
      __syncthreads();
    }
  }
  order[t] = comp[t] & 511;
}

// ---------------------------------------------------------------------------
// Kernel 2: GRU recurrence. 256 blocks x 512 threads, one block per CU.
// Thread (i = tid&127, kc = tid>>7): split-K matvec with weights register-
// resident (96 VGPRs/thread = the whole 192KB w_hh spread across the CU).
//
// ROUND HISTORY (why the attribute below is load-bearing):
//   r1: plain loads             -> compiler sank loads into loop (VGPR 76, L2-bound)
//   r2: out-of-loop asm pin     -> RA SPILLED pinned values to scratch (VGPR 76)
//   r3: in-loop asm pin         -> same spill; cold dispatch showed 45 GB scratch
//                                  traffic = 96 floats reloaded per thread-step.
//   r4: waves_per_eu(2,2) + float4 asm pin -> compile error (tied indirect
//       register inputs); pin must be on SCALAR components.
// The allocator was chasing >4 waves/EU occupancy. amdgpu_waves_per_eu(2,2)
// caps occupancy at exactly our design point (8 waves = 1 block / CU), giving
// RA a 256-VGPR budget and zero incentive to spill ~170 live values.
// ---------------------------------------------------------------------------
__global__ __launch_bounds__(512)
__attribute__((amdgpu_waves_per_eu(2, 2)))
void gru_main(
    const float* __restrict__ x, const int* __restrict__ lengths,
    const float* __restrict__ w_ih, const float* __restrict__ w_hh,
    const float* __restrict__ b_ih, const float* __restrict__ b_hh,
    const float* __restrict__ head_w, const float* __restrict__ head_b,
    const int* __restrict__ order, float* __restrict__ out) {
  __shared__ __align__(16) float hs[HH];        // current hidden state
  __shared__ float parts[3][4][HH];             // split-K partials
  __shared__ __align__(16) float xrow[TT * 2];  // staged x row (8 KB)

  const int tid = threadIdx.x;
  const int i  = tid & (HH - 1);  // output row within a gate
  const int kc = tid >> 7;        // k-chunk 0..3 (wave-pair uniform)

  // --- one-time: weights into registers, producers made opaque (scalar pins) ---
  float4 wv[3][8];  // wv[g][q] = w_hh[g*128 + i][kc*32 + 4q .. +3]
#pragma unroll
  for (int g = 0; g < 3; ++g)
#pragma unroll
    for (int q = 0; q < 8; ++q) {
      wv[g][q] = *reinterpret_cast<const float4*>(
          &w_hh[(g * HH + i) * HH + kc * 32 + q * 4]);
      asm volatile("" : "+v"(wv[g][q].x), "+v"(wv[g][q].y),
                        "+v"(wv[g][q].z), "+v"(wv[g][q].w));
    }

  // --- phase-2 constants ---
  float wi0[3], wi1[3], bi[3], bh[3];
#pragma unroll
  for (int g = 0; g < 3; ++g) {
    wi0[g] = w_ih[(g * HH + i) * 2 + 0];
    wi1[g] = w_ih[(g * HH + i) * 2 + 1];
    bi[g]  = b_ih[g * HH + i];
    bh[g]  = b_hh[g * HH + i];
  }
  const float hw = head_w[i];
  const float hb = head_b[0];

  for (int pb = 0; pb < 2; ++pb) {
    const int slot = pb ? (BB - 1 - (int)blockIdx.x) : (int)blockIdx.x;
    const int b = order[slot];
    const int len = lengths[b];  // in [1, 1024]

    // stage this batch's x row (coalesced) + init h
    for (int ofs = tid; ofs < len * 2; ofs += 512)
      xrow[ofs] = x[(size_t)b * (TT * 2) + ofs];
    if (tid < HH) hs[tid] = 0.0f;
    __syncthreads();

    for (int t = 0; t < len; ++t) {
      // ---- phase 1: split-K matvec (h chunk broadcast within wave) ----
      float4 h4[8];
#pragma unroll
      for (int q = 0; q < 8; ++q)
        h4[q] = *reinterpret_cast<const float4*>(&hs[kc * 32 + q * 4]);
      float pr = 0.f, pz = 0.f, pn = 0.f;
#pragma unroll
      for (int q = 0; q < 8; ++q) {
        pr = fmaf(wv[0][q].x, h4[q].x, pr); pr = fmaf(wv[0][q].y, h4[q].y, pr);
        pr = fmaf(wv[0][q].z, h4[q].z, pr); pr = fmaf(wv[0][q].w, h4[q].w, pr);
        pz = fmaf(wv[1][q].x, h4[q].x, pz); pz = fmaf(wv[1][q].y, h4[q].y, pz);
        pz = fmaf(wv[1][q].z, h4[q].z, pz); pz = fmaf(wv[1][q].w, h4[q].w, pz);
        pn = fmaf(wv[2][q].x, h4[q].x, pn); pn = fmaf(wv[2][q].y, h4[q].y, pn);
        pn = fmaf(wv[2][q].z, h4[q].z, pn); pn = fmaf(wv[2][q].w, h4[q].w, pn);
      }
      parts[0][kc][i] = pr;
      parts[1][kc][i] = pz;
      parts[2][kc][i] = pn;
      __syncthreads();

      // ---- phase 2: reduce + gates + h update, threads 0..127 ----
      if (tid < HH) {
        float gr = bh[0] + parts[0][0][tid] + parts[0][1][tid] +
                   parts[0][2][tid] + parts[0][3][tid];
        float gz = bh[1] + parts[1][0][tid] + parts[1][1][tid] +
                   parts[1][2][tid] + parts[1][3][tid];
        float gn = bh[2] + parts[2][0][tid] + parts[2][1][tid] +
                   parts[2][2][tid] + parts[2][3][tid];
        const float x0 = xrow[t * 2 + 0];
        const float x1 = xrow[t * 2 + 1];
        const float ar = bi[0] + x0 * wi0[0] + x1 * wi1[0] + gr;
        const float az = bi[1] + x0 * wi0[1] + x1 * wi1[1] + gz;
        const float an = bi[2] + x0 * wi0[2] + x1 * wi1[2];
        const float r = 1.0f / (1.0f + __expf(-ar));
        const float z = 1.0f / (1.0f + __expf(-az));
        const float a = an + r * gn;          // tanh argument
        const float e2 = __expf(-2.0f * a);
        const float n = (1.0f - e2) / (1.0f + e2);
        hs[tid] = (1.0f - z) * n + z * hs[tid];
      }
      __syncthreads();
    }

    // ---- head: out[b] = dot(h, head_w) + head_b ----
    if (tid < HH) parts[0][0][tid] = hs[tid] * hw;
    __syncthreads();
    if (tid == 0) {
      float s = hb;
      for (int q = 0; q < HH; ++q) s += parts[0][0][q];
      out[b] = s;
    }
    __syncthreads();  // protect hs/parts before next batch reuses them
  }
}

extern "C" void kernel_launch(void* const* d_in, const int* in_sizes, int n_in,
                              void* d_out, int out_size, void* d_ws, size_t ws_size,
                              hipStream_t stream) {
  const float* x       = (const float*)d_in[0];
  const int*   lengths = (const int*)d_in[1];
  const float* w_ih    = (const float*)d_in[2];
  const float* w_hh    = (const float*)d_in[3];
  const float* b_ih    = (const float*)d_in[4];
  const float* b_hh    = (const float*)d_in[5];
  const float* head_w  = (const float*)d_in[6];
  const float* head_b  = (const float*)d_in[7];
  float* out = (float*)d_out;
  int* order = (int*)d_ws;  // 512 ints of scratch

  sort_kernel<<<1, 512, 0, stream>>>(lengths, order);
  gru_main<<<256, 512, 0, stream>>>(x, lengths, w_ih, w_hh, b_ih, b_hh,
                                    head_w, head_b, order, out);
}

// Round 6
// 674.908 us; speedup vs baseline: 1.3519x; 1.0099x over previous
//
#include <hip/hip_runtime.h>
#include <math.h>

#define BB 512   // batch
#define TT 1024  // max seq len
#define HH 128   // hidden

// ---------------------------------------------------------------------------
// Kernel 1: bitonic sort of (length, idx) composite keys, descending.
// Load-balance only; any permutation is still correct.
// ---------------------------------------------------------------------------
__global__ __launch_bounds__(512) void sort_kernel(const int* __restrict__ lengths,
                                                   int* __restrict__ order) {
  __shared__ int comp[BB];
  const int t = threadIdx.x;
  comp[t] = (lengths[t] << 9) | t;  // unique composite keys
  __syncthreads();
  for (int k = 2; k <= BB; k <<= 1) {
    for (int j = k >> 1; j > 0; j >>= 1) {
      int ixj = t ^ j;
      if (ixj > t) {
        int a = comp[t], b = comp[ixj];
        bool descBlock = ((t & k) == 0);
        bool doSwap = descBlock ? (a < b) : (a > b);
        if (doSwap) { comp[t] = b; comp[ixj] = a; }
      }
      __syncthreads();
    }
  }
  order[t] = comp[t] & 511;
}

// ---------------------------------------------------------------------------
// Kernel 2: GRU recurrence. 256 blocks x 1024 threads (16 waves), 1 block/CU.
// Thread (i = tid&127, kc = tid>>7, 8 chunks of 16): split-K matvec with only
// 48 weight floats per thread.
//
// ROUND HISTORY (why 1024 threads / 48 weights):
//   r1-r5: 512-thread design needed 96 resident weight floats/thread; across
//   plain loads, asm pins (out-of-loop, in-loop) and waves_per_eu(2,2) the
//   allocator NEVER allocated more than 88 VGPRs -> weights re-fetched from
//   L1/L2 every step (192KB/CU-step ~ 1400cyc, the measured 1716 cyc/step).
//   This design needs only 48+~50 live regs ~= 100, under the 128-VGPR cap
//   that 16 waves/CU implies -- resident even with round-5's allocator
//   behavior. waves_per_eu(4,4) pins the budget at exactly 128.
// ---------------------------------------------------------------------------
__global__ __launch_bounds__(1024)
__attribute__((amdgpu_waves_per_eu(4, 4)))
void gru_main(
    const float* __restrict__ x, const int* __restrict__ lengths,
    const float* __restrict__ w_ih, const float* __restrict__ w_hh,
    const float* __restrict__ b_ih, const float* __restrict__ b_hh,
    const float* __restrict__ head_w, const float* __restrict__ head_b,
    const int* __restrict__ order, float* __restrict__ out) {
  __shared__ __align__(16) float hs[HH];        // current hidden state
  __shared__ float parts[3][8][HH];             // split-K partials (12 KB)
  __shared__ __align__(16) float xrow[TT * 2];  // staged x row (8 KB)

  const int tid = threadIdx.x;
  const int i  = tid & (HH - 1);  // output row within a gate
  const int kc = tid >> 7;        // k-chunk 0..7 (16 floats), wave-uniform

  // --- one-time: weights into registers (48 floats), producers opaque ---
  float4 wv[3][4];  // wv[g][q] = w_hh[g*128 + i][kc*16 + 4q .. +3]
#pragma unroll
  for (int g = 0; g < 3; ++g)
#pragma unroll
    for (int q = 0; q < 4; ++q) {
      wv[g][q] = *reinterpret_cast<const float4*>(
          &w_hh[(g * HH + i) * HH + kc * 16 + q * 4]);
      asm volatile("" : "+v"(wv[g][q].x), "+v"(wv[g][q].y),
                        "+v"(wv[g][q].z), "+v"(wv[g][q].w));
    }

  // --- phase-2 constants ---
  float wi0[3], wi1[3], bi[3], bh[3];
#pragma unroll
  for (int g = 0; g < 3; ++g) {
    wi0[g] = w_ih[(g * HH + i) * 2 + 0];
    wi1[g] = w_ih[(g * HH + i) * 2 + 1];
    bi[g]  = b_ih[g * HH + i];
    bh[g]  = b_hh[g * HH + i];
  }
  const float hw = head_w[i];
  const float hb = head_b[0];

  for (int pb = 0; pb < 2; ++pb) {
    const int slot = pb ? (BB - 1 - (int)blockIdx.x) : (int)blockIdx.x;
    const int b = order[slot];
    const int len = lengths[b];  // in [1, 1024]

    // stage this batch's x row (coalesced) + init h
    for (int ofs = tid; ofs < len * 2; ofs += 1024)
      xrow[ofs] = x[(size_t)b * (TT * 2) + ofs];
    if (tid < HH) hs[tid] = 0.0f;
    __syncthreads();

    for (int t = 0; t < len; ++t) {
      // ---- phase 1: split-K matvec (h chunk broadcast within wave) ----
      float4 h4[4];
#pragma unroll
      for (int q = 0; q < 4; ++q)
        h4[q] = *reinterpret_cast<const float4*>(&hs[kc * 16 + q * 4]);
      float pr = 0.f, pz = 0.f, pn = 0.f;
#pragma unroll
      for (int q = 0; q < 4; ++q) {
        pr = fmaf(wv[0][q].x, h4[q].x, pr); pr = fmaf(wv[0][q].y, h4[q].y, pr);
        pr = fmaf(wv[0][q].z, h4[q].z, pr); pr = fmaf(wv[0][q].w, h4[q].w, pr);
        pz = fmaf(wv[1][q].x, h4[q].x, pz); pz = fmaf(wv[1][q].y, h4[q].y, pz);
        pz = fmaf(wv[1][q].z, h4[q].z, pz); pz = fmaf(wv[1][q].w, h4[q].w, pz);
        pn = fmaf(wv[2][q].x, h4[q].x, pn); pn = fmaf(wv[2][q].y, h4[q].y, pn);
        pn = fmaf(wv[2][q].z, h4[q].z, pn); pn = fmaf(wv[2][q].w, h4[q].w, pn);
      }
      parts[0][kc][i] = pr;
      parts[1][kc][i] = pz;
      parts[2][kc][i] = pn;
      __syncthreads();

      // ---- phase 2: reduce 8 partials/gate + gates + h update (tid<128) ----
      if (tid < HH) {
        float gr = bh[0], gz = bh[1], gn = bh[2];
#pragma unroll
        for (int c = 0; c < 8; ++c) gr += parts[0][c][tid];
#pragma unroll
        for (int c = 0; c < 8; ++c) gz += parts[1][c][tid];
#pragma unroll
        for (int c = 0; c < 8; ++c) gn += parts[2][c][tid];
        const float x0 = xrow[t * 2 + 0];
        const float x1 = xrow[t * 2 + 1];
        const float ar = bi[0] + x0 * wi0[0] + x1 * wi1[0] + gr;
        const float az = bi[1] + x0 * wi0[1] + x1 * wi1[1] + gz;
        const float an = bi[2] + x0 * wi0[2] + x1 * wi1[2];
        const float r = 1.0f / (1.0f + __expf(-ar));
        const float z = 1.0f / (1.0f + __expf(-az));
        const float a = an + r * gn;          // tanh argument
        const float e2 = __expf(-2.0f * a);
        const float n = (1.0f - e2) / (1.0f + e2);
        hs[tid] = (1.0f - z) * n + z * hs[tid];
      }
      __syncthreads();
    }

    // ---- head: out[b] = dot(h, head_w) + head_b ----
    if (tid < HH) parts[0][0][tid] = hs[tid] * hw;
    __syncthreads();
    if (tid == 0) {
      float s = hb;
      for (int q = 0; q < HH; ++q) s += parts[0][0][q];
      out[b] = s;
    }
    __syncthreads();  // protect hs/parts before next batch reuses them
  }
}

extern "C" void kernel_launch(void* const* d_in, const int* in_sizes, int n_in,
                              void* d_out, int out_size, void* d_ws, size_t ws_size,
                              hipStream_t stream) {
  const float* x       = (const float*)d_in[0];
  const int*   lengths = (const int*)d_in[1];
  const float* w_ih    = (const float*)d_in[2];
  const float* w_hh    = (const float*)d_in[3];
  const float* b_ih    = (const float*)d_in[4];
  const float* b_hh    = (const float*)d_in[5];
  const float* head_w  = (const float*)d_in[6];
  const float* head_b  = (const float*)d_in[7];
  float* out = (float*)d_out;
  int* order = (int*)d_ws;  // 512 ints of scratch

  sort_kernel<<<1, 512, 0, stream>>>(lengths, order);
  gru_main<<<256, 1024, 0, stream>>>(x, lengths, w_ih, w_hh, b_ih, b_hh,
                                     head_w, head_b, order, out);
}